// Round 14
// baseline (109.754 us; speedup 1.0000x reference)
//
#include <hip/hip_runtime.h>
#include <math.h>
#include <stdint.h>

typedef __bf16 bf16;
typedef __bf16 bf16x8 __attribute__((ext_vector_type(8)));
typedef __bf16 bf16x4 __attribute__((ext_vector_type(4)));
typedef float f32x4 __attribute__((ext_vector_type(4)));
typedef unsigned int u32;

// element index into a [rows][64] bf16 tile, XOR-swizzled in 16B (8-elem) chunks
__device__ __forceinline__ int swz(int row, int chunk) {
    return row * 64 + ((chunk ^ (row & 7)) << 3);
}

// async 16B global->LDS; lds must be wave-uniform base (HW adds lane*16)
__device__ __forceinline__ void gld16(void* lds, const void* g) {
    __builtin_amdgcn_global_load_lds(
        (const __attribute__((address_space(1))) u32*)g,
        (__attribute__((address_space(3))) u32*)lds, 16, 0, 0);
}

// 8-wave staging of a 64x64 bf16 tile: each wave issues ONE gld16 covering 8
// rows. Linear LDS dest + inverse-XOR on the SOURCE chunk so swizzled reads
// see LDS[row][chunk^(row&7)] == src[row][chunk].
__device__ __forceinline__ void stage8(bf16* dst, const bf16* src, size_t srcStride,
                                       int w, int l) {
    const int br = w * 8;
    const int r = br + (l >> 3);
    const int gs = (l & 7) ^ (r & 7);
    gld16(dst + br * 64, src + (size_t)r * srcStride + gs * 8);
}

// ONE prep launch: blocks [0,512) transpose w2 -> w2t bf16; [512,1024) cast the
// three square weights; [1024,2048) cast x. All branches block-uniform.
__global__ __launch_bounds__(256) void prep_all_k(const float* __restrict__ x,  bf16* __restrict__ xb,
                                                  const float* __restrict__ w1_w, bf16* __restrict__ w1b,
                                                  const float* __restrict__ value_w, bf16* __restrict__ vwb,
                                                  const float* __restrict__ proj_w, bf16* __restrict__ pwb,
                                                  const float* __restrict__ w2, bf16* __restrict__ w2t,
                                                  int nx, int nw)
{
    const int bx = blockIdx.x;
    const int t = threadIdx.x;
    if (bx < 512) {
        constexpr int M = 2048;
        __shared__ float Tf[64][65];
        const int h = bx >> 5, m0 = (bx & 31) * 64;
        {
            const int dr = t >> 4, c4 = (t & 15) * 4;
            #pragma unroll
            for (int it = 0; it < 4; ++it) {
                const int d = dr + it * 16;
                float4 v = *(const float4*)(w2 + ((size_t)h * 64 + d) * M + m0 + c4);
                Tf[d][c4] = v.x; Tf[d][c4 + 1] = v.y; Tf[d][c4 + 2] = v.z; Tf[d][c4 + 3] = v.w;
            }
        }
        __syncthreads();
        const int m = t >> 2;
        #pragma unroll
        for (int it = 0; it < 2; ++it) {
            const int ch = (t & 3) + it * 4;
            bf16x8 o;
            #pragma unroll
            for (int j = 0; j < 8; ++j) o[j] = (bf16)Tf[ch * 8 + j][m];
            *(bf16x8*)(w2t + ((size_t)h * M + m0 + m) * 64 + ch * 8) = o;
        }
    } else if (bx < 1024) {
        const int stride = 512 * 256 * 4;
        for (int i = ((bx - 512) * 256 + t) * 4; i < nw; i += stride) {
            float4 v0 = *(const float4*)(w1_w + i);
            float4 v1 = *(const float4*)(value_w + i);
            float4 v2 = *(const float4*)(proj_w + i);
            bf16x4 o0 = {(bf16)v0.x, (bf16)v0.y, (bf16)v0.z, (bf16)v0.w};
            bf16x4 o1 = {(bf16)v1.x, (bf16)v1.y, (bf16)v1.z, (bf16)v1.w};
            bf16x4 o2 = {(bf16)v2.x, (bf16)v2.y, (bf16)v2.z, (bf16)v2.w};
            *(bf16x4*)(w1b + i) = o0;
            *(bf16x4*)(vwb + i) = o1;
            *(bf16x4*)(pwb + i) = o2;
        }
    } else {
        const int stride = 1024 * 256 * 4;
        for (int i = ((bx - 1024) * 256 + t) * 4; i < nx; i += stride) {
            float4 v = *(const float4*)(x + i);
            bf16x4 o = {(bf16)v.x, (bf16)v.y, (bf16)v.z, (bf16)v.w};
            *(bf16x4*)(xb + i) = o;
        }
    }
}

// 128x128x64 bf16 MFMA GEMM (R9-verified: counted-vmcnt double buffer).
__global__ __launch_bounds__(256, 2) void gemm_bf16_k(const bf16* __restrict__ A,
                                                   const bf16* __restrict__ Bw,
                                                   const float* __restrict__ bias,
                                                   const float* __restrict__ bias2,
                                                   float* __restrict__ C0,
                                                   bf16* __restrict__ CK,
                                                   bf16* __restrict__ CV,
                                                   int M, int N, int K, int mode, int Ns)
{
    __shared__ __align__(16) bf16 As[2][128 * 64];
    __shared__ __align__(16) bf16 Bs[2][128 * 64];
    const int tid = threadIdx.x;
    const int w = tid >> 6, l = tid & 63;
    const int wr = w >> 1, wc = w & 1;
    const int lc = l & 15, lg = l >> 4;
    const int row0 = blockIdx.y * 128, col0 = blockIdx.x * 128;

    f32x4 acc[4][4] = {};

    const int nk = K >> 6;
    auto issue = [&](int buf, int k0) {
        #pragma unroll
        for (int i = 0; i < 4; ++i) {
            const int br = (w * 4 + i) * 8;
            const int r = br + (l >> 3);
            const int gs = (l & 7) ^ (r & 7);
            gld16(&As[buf][br * 64], A  + (size_t)(row0 + r) * K + k0 + gs * 8);
            gld16(&Bs[buf][br * 64], Bw + (size_t)(col0 + r) * K + k0 + gs * 8);
        }
    };

    issue(0, 0);
    int cur = 0;
    for (int kt = 0; kt < nk; ++kt) {
        if (kt + 1 < nk) {
            issue(cur ^ 1, (kt + 1) << 6);
            asm volatile("s_waitcnt vmcnt(8)" ::: "memory");
        } else {
            asm volatile("s_waitcnt vmcnt(0)" ::: "memory");
        }
        __builtin_amdgcn_s_barrier();
        #pragma unroll
        for (int ks = 0; ks < 2; ++ks) {
            bf16x8 af[4], bfv[4];
            #pragma unroll
            for (int i = 0; i < 4; ++i) {
                af[i]  = *(const bf16x8*)&As[cur][swz(wr * 64 + i * 16 + lc, ks * 4 + lg)];
                bfv[i] = *(const bf16x8*)&Bs[cur][swz(wc * 64 + i * 16 + lc, ks * 4 + lg)];
            }
            #pragma unroll
            for (int mi = 0; mi < 4; ++mi)
                #pragma unroll
                for (int ni = 0; ni < 4; ++ni)
                    acc[mi][ni] = __builtin_amdgcn_mfma_f32_16x16x32_bf16(af[mi], bfv[ni], acc[mi][ni], 0, 0, 0);
        }
        asm volatile("s_waitcnt lgkmcnt(0)" ::: "memory");
        __builtin_amdgcn_s_barrier();
        cur ^= 1;
    }

    #pragma unroll
    for (int ni = 0; ni < 4; ++ni) {
        const int col = col0 + wc * 64 + ni * 16 + lc;
        #pragma unroll
        for (int mi = 0; mi < 4; ++mi) {
            const int rowb = row0 + wr * 64 + mi * 16 + lg * 4;
            f32x4 v = acc[mi][ni];
            if (mode == 0) {
                const float bv = bias[col];
                #pragma unroll
                for (int r = 0; r < 4; ++r)
                    C0[(size_t)(rowb + r) * N + col] = v[r] + bv;
            } else if (col < Ns) {
                const float bv = bias[col];
                #pragma unroll
                for (int r = 0; r < 4; ++r)
                    CK[(size_t)(rowb + r) * Ns + col] = (bf16)fmaxf(v[r] + bv, 0.f);
            } else {
                const float bv = bias2[col - Ns];
                const int b = rowb >> 11, tt = rowb & 2047;   // T = 2048
                bf16x4 o = {(bf16)(v[0] + bv), (bf16)(v[1] + bv),
                            (bf16)(v[2] + bv), (bf16)(v[3] + bv)};
                *(bf16x4*)(CV + ((size_t)b * Ns + (col - Ns)) * 2048 + tt) = o;
            }
        }
    }
}

// one SWAPPED QK -> softmax -> PV step on the staged 64x64 W/V tile.
// S^T = mfma(A=W^T s-rows, B=K q-cols): sv[st][r] = S[s=st*16+lg*4+r][q=wq*16+lc]
// P stored [q=16][s=64] with ROW STRIDE 72 elems (144B): bank base rotates
// with q-row (36 mod 32 = 4/row) -> kills the stride-64 4-way read alias.
// T5: setprio(1) around the MFMA clusters (attn-positive per m191).
__device__ __forceinline__ void tile_step(bf16x8 kf0, bf16x8 kf1,
                                          const bf16* Wb, const bf16* Vb,
                                          bf16* Pw, const float* b2l, int s0,
                                          f32x4 (&acc)[4], float& lsum,
                                          bool diag, int lc, int lg, int wq)
{
    // S^T = W . K + b2 (bias varies along s = MFMA rows = f32x4 elements)
    f32x4 sv[4];
    #pragma unroll
    for (int st = 0; st < 4; ++st) {
        const float4 b4 = *(const float4*)&b2l[s0 + st * 16 + lg * 4];
        sv[st] = {b4.x, b4.y, b4.z, b4.w};
    }
    __builtin_amdgcn_s_setprio(1);
    #pragma unroll
    for (int st = 0; st < 4; ++st) {
        bf16x8 wb0 = *(const bf16x8*)&Wb[swz(st * 16 + lc, lg)];
        bf16x8 wb1 = *(const bf16x8*)&Wb[swz(st * 16 + lc, 4 + lg)];
        sv[st] = __builtin_amdgcn_mfma_f32_16x16x32_bf16(wb0, kf0, sv[st], 0, 0, 0);
        sv[st] = __builtin_amdgcn_mfma_f32_16x16x32_bf16(wb1, kf1, sv[st], 0, 0, 0);
    }
    __builtin_amdgcn_s_setprio(0);
    // exp (exact, no max: |S| bounded small), causal mask, packed P write
    const int qv = wq * 16 + lc;
    #pragma unroll
    for (int st = 0; st < 4; ++st) {
        float e[4];
        #pragma unroll
        for (int r = 0; r < 4; ++r) {
            const int sidx = st * 16 + lg * 4 + r;
            float ev = __expf(sv[st][r]);
            if (diag && sidx > qv) ev = 0.f;
            e[r] = ev;
            lsum += ev;
        }
        bf16x4 pw = {(bf16)e[0], (bf16)e[1], (bf16)e[2], (bf16)e[3]};
        const int chunk = st * 2 + (lg >> 1);
        *(bf16x4*)&Pw[lc * 72 + ((chunk ^ (lc & 7)) << 3) + ((lg & 1) << 2)] = pw;
    }
    // O += P . V
    __builtin_amdgcn_s_setprio(1);
    #pragma unroll
    for (int ks = 0; ks < 2; ++ks) {
        bf16x8 pf = *(const bf16x8*)&Pw[lc * 72 + (((ks * 4 + lg) ^ (lc & 7)) << 3)];
        #pragma unroll
        for (int dt = 0; dt < 4; ++dt) {
            bf16x8 vv = *(const bf16x8*)&Vb[swz(dt * 16 + lc, ks * 4 + lg)];
            acc[dt] = __builtin_amdgcn_mfma_f32_16x16x32_bf16(pf, vv, acc[dt], 0, 0, 0);
        }
    }
    __builtin_amdgcn_s_setprio(0);
}

// v9 structure (R9-verified, best measured): 512 threads; waves 0-3 -> q-tile
// 31-j, waves 4-7 -> q-tile j, shared 3-buffer W/V ring, counted vmcnt, b2 in
// LDS, swapped-QK packed-P tile_step (+setprio, +P-pad72 this round).
__global__ __launch_bounds__(512, 4) void synth_attn_v9(const bf16* __restrict__ Kb,
                                                        const bf16* __restrict__ VT,
                                                        const bf16* __restrict__ w2t,
                                                        const float* __restrict__ b2,
                                                        bf16* __restrict__ Ob)
{
    constexpr int T = 2048, C = 1024, M = 2048;
    __shared__ __align__(16) bf16 Wl[3][64 * 64];
    __shared__ __align__(16) bf16 Vl[3][64 * 64];
    __shared__ __align__(16) bf16 Pl[8][16 * 72];   // stride-72 rows (bank rotate)
    __shared__ float b2l[M];
    const int tid = threadIdx.x;
    const int w = tid >> 6, l = tid & 63;
    const int lc = l & 15, lg = l >> 4;
    const int wq = w & 3, wt = w >> 2;

    const int bx = blockIdx.x;
    const int j = bx & 15;
    const int bh = bx >> 4;
    const int h = bh & 15, b = bh >> 4;
    const int tA = j, tB = 31 - j;
    const int myT = wt ? tA : tB;
    const int t0 = myT * 64;

    // b2 -> LDS (512 threads x 4 floats = 2048)
    *(float4*)&b2l[tid * 4] = *(const float4*)(b2 + tid * 4);
    __syncthreads();

    const bf16* Wgt = w2t + (size_t)h * M * 64;            // [s][64] rows
    const bf16* Vgt = VT + ((size_t)b * C + h * 64) * T;   // [d][T] rows
    bf16* Pw = &Pl[w][0];

    // K fragments for this wave's 16 q-rows (B-operand of swapped QK)
    const bf16* Kg = Kb + (size_t)(b * T + t0 + wq * 16 + lc) * C + h * 64;
    const bf16x8 kf0 = *(const bf16x8*)(Kg + lg * 8);
    const bf16x8 kf1 = *(const bf16x8*)(Kg + 32 + lg * 8);

    // prologue: stage tiles 0 and 1 (tB >= 16, both exist)
    stage8(&Wl[0][0], Wgt, 64, w, l);
    stage8(&Vl[0][0], Vgt, T, w, l);
    stage8(&Wl[1][0], Wgt + (size_t)64 * 64, 64, w, l);
    stage8(&Vl[1][0], Vgt + 64, T, w, l);

    f32x4 acc[4] = {};
    float lsum = 0.f;

    int cur = 0;
    for (int sb = 0; sb <= tB; ++sb) {
        const int s0 = sb * 64;
        // my 2 loads for tile sb done; tile sb+1's 2 may stay in flight
        if (sb < tB) asm volatile("s_waitcnt vmcnt(2)" ::: "memory");
        else         asm volatile("s_waitcnt vmcnt(0)" ::: "memory");
        __builtin_amdgcn_s_barrier();

        if (sb <= myT)
            tile_step(kf0, kf1, &Wl[cur][0], &Vl[cur][0], Pw, b2l, s0,
                      acc, lsum, sb == myT, lc, lg, wq);

        // stage tile sb+2 into buf (sb+2)%3: its readers crossed this barrier
        if (sb + 2 <= tB) {
            int nx = cur + 2; if (nx >= 3) nx -= 3;
            stage8(&Wl[nx][0], Wgt + (size_t)(s0 + 128) * 64, 64, w, l);
            stage8(&Vl[nx][0], Vgt + (s0 + 128), T, w, l);
        }
        if (++cur == 3) cur = 0;
    }

    // epilogue: lane's lsum is the partial row-sum for q=wq*16+lc; reduce over
    // the 4 lanes sharing lc (xor 16/32), then redistribute to the acc layout
    // (q = lg*4+r) via shfl from lane q.
    float ls = lsum;
    ls += __shfl_xor(ls, 16);
    ls += __shfl_xor(ls, 32);
    #pragma unroll
    for (int r = 0; r < 4; ++r) {
        const float inv = 1.f / __shfl(ls, lg * 4 + r);
        bf16* dst = Ob + (size_t)(b * T + t0 + wq * 16 + lg * 4 + r) * C + h * 64;
        #pragma unroll
        for (int dt = 0; dt < 4; ++dt)
            dst[dt * 16 + lc] = (bf16)(acc[dt][r] * inv);
    }
}

extern "C" void kernel_launch(void* const* d_in, const int* in_sizes, int n_in,
                              void* d_out, int out_size, void* d_ws, size_t ws_size,
                              hipStream_t stream) {
    const float* x       = (const float*)d_in[0];
    const float* w1_w    = (const float*)d_in[1];
    const float* w1_b    = (const float*)d_in[2];
    const float* w2      = (const float*)d_in[3];
    const float* b2      = (const float*)d_in[4];
    const float* value_w = (const float*)d_in[5];
    const float* value_b = (const float*)d_in[6];
    const float* proj_w  = (const float*)d_in[7];
    const float* proj_b  = (const float*)d_in[8];

    const int B = 2, T = 2048, C = 1024, H = 16, M = 2048;
    const int R = B * T;   // 4096

    bf16* xb  = (bf16*)d_ws;                  // [R][C]
    bf16* w1b = xb  + (size_t)R * C;          // [C][C]   } contiguous ->
    bf16* vwb = w1b + (size_t)C * C;          // [C][C]   } fused B [2C][C]
    bf16* w2t = vwb + (size_t)C * C;          // [H][M][64]
    bf16* pwb = w2t + (size_t)H * M * 64;     // [C][C]
    bf16* Kb  = pwb + (size_t)C * C;          // [R][C]
    bf16* VTb = Kb  + (size_t)R * C;          // [B][C][T]
    bf16* Ob  = VTb + (size_t)R * C;          // [R][C]    total 42 MB

    // one prep launch: w2 transpose + 3 weight casts + x cast
    prep_all_k<<<2048, 256, 0, stream>>>(x, xb, w1_w, w1b, value_w, vwb,
                                         proj_w, pwb, w2, w2t, R * C, C * C);

    // fused K/V GEMM: N = 2C, B-operand = [w1b ; vwb]
    gemm_bf16_k<<<dim3(2 * C / 128, R / 128), 256, 0, stream>>>(
        xb, w1b, w1_b, value_b, nullptr, Kb, VTb, R, 2 * C, C, 1, C);

    synth_attn_v9<<<dim3(512), 512, 0, stream>>>(Kb, VTb, w2t, b2, Ob);

    gemm_bf16_k<<<dim3(C / 128, R / 128), 256, 0, stream>>>(
        Ob, pwb, proj_b, nullptr, (float*)d_out, nullptr, nullptr, R, C, C, 0, C);
}

// Round 15
// 98.825 us; speedup vs baseline: 1.1106x; 1.1106x over previous
//
#include <hip/hip_runtime.h>
#include <math.h>
#include <stdint.h>

typedef __bf16 bf16;
typedef __bf16 bf16x8 __attribute__((ext_vector_type(8)));
typedef __bf16 bf16x4 __attribute__((ext_vector_type(4)));
typedef float f32x4 __attribute__((ext_vector_type(4)));
typedef unsigned int u32;

// element index into a [rows][64] bf16 tile, XOR-swizzled in 16B (8-elem) chunks
__device__ __forceinline__ int swz(int row, int chunk) {
    return row * 64 + ((chunk ^ (row & 7)) << 3);
}

// async 16B global->LDS; lds must be wave-uniform base (HW adds lane*16)
__device__ __forceinline__ void gld16(void* lds, const void* g) {
    __builtin_amdgcn_global_load_lds(
        (const __attribute__((address_space(1))) u32*)g,
        (__attribute__((address_space(3))) u32*)lds, 16, 0, 0);
}

// 8-wave staging of a 64x64 bf16 tile: each wave issues ONE gld16 covering 8
// rows. Linear LDS dest + inverse-XOR on the SOURCE chunk so swizzled reads
// see LDS[row][chunk^(row&7)] == src[row][chunk].
__device__ __forceinline__ void stage8(bf16* dst, const bf16* src, size_t srcStride,
                                       int w, int l) {
    const int br = w * 8;
    const int r = br + (l >> 3);
    const int gs = (l & 7) ^ (r & 7);
    gld16(dst + br * 64, src + (size_t)r * srcStride + gs * 8);
}

// ONE prep launch: blocks [0,512) transpose w2 -> w2t bf16; [512,1024) cast the
// three square weights; [1024,2048) cast x. All branches block-uniform.
__global__ __launch_bounds__(256) void prep_all_k(const float* __restrict__ x,  bf16* __restrict__ xb,
                                                  const float* __restrict__ w1_w, bf16* __restrict__ w1b,
                                                  const float* __restrict__ value_w, bf16* __restrict__ vwb,
                                                  const float* __restrict__ proj_w, bf16* __restrict__ pwb,
                                                  const float* __restrict__ w2, bf16* __restrict__ w2t,
                                                  int nx, int nw)
{
    const int bx = blockIdx.x;
    const int t = threadIdx.x;
    if (bx < 512) {
        constexpr int M = 2048;
        __shared__ float Tf[64][65];
        const int h = bx >> 5, m0 = (bx & 31) * 64;
        {
            const int dr = t >> 4, c4 = (t & 15) * 4;
            #pragma unroll
            for (int it = 0; it < 4; ++it) {
                const int d = dr + it * 16;
                float4 v = *(const float4*)(w2 + ((size_t)h * 64 + d) * M + m0 + c4);
                Tf[d][c4] = v.x; Tf[d][c4 + 1] = v.y; Tf[d][c4 + 2] = v.z; Tf[d][c4 + 3] = v.w;
            }
        }
        __syncthreads();
        const int m = t >> 2;
        #pragma unroll
        for (int it = 0; it < 2; ++it) {
            const int ch = (t & 3) + it * 4;
            bf16x8 o;
            #pragma unroll
            for (int j = 0; j < 8; ++j) o[j] = (bf16)Tf[ch * 8 + j][m];
            *(bf16x8*)(w2t + ((size_t)h * M + m0 + m) * 64 + ch * 8) = o;
        }
    } else if (bx < 1024) {
        const int stride = 512 * 256 * 4;
        for (int i = ((bx - 512) * 256 + t) * 4; i < nw; i += stride) {
            float4 v0 = *(const float4*)(w1_w + i);
            float4 v1 = *(const float4*)(value_w + i);
            float4 v2 = *(const float4*)(proj_w + i);
            bf16x4 o0 = {(bf16)v0.x, (bf16)v0.y, (bf16)v0.z, (bf16)v0.w};
            bf16x4 o1 = {(bf16)v1.x, (bf16)v1.y, (bf16)v1.z, (bf16)v1.w};
            bf16x4 o2 = {(bf16)v2.x, (bf16)v2.y, (bf16)v2.z, (bf16)v2.w};
            *(bf16x4*)(w1b + i) = o0;
            *(bf16x4*)(vwb + i) = o1;
            *(bf16x4*)(pwb + i) = o2;
        }
    } else {
        const int stride = 1024 * 256 * 4;
        for (int i = ((bx - 1024) * 256 + t) * 4; i < nx; i += stride) {
            float4 v = *(const float4*)(x + i);
            bf16x4 o = {(bf16)v.x, (bf16)v.y, (bf16)v.z, (bf16)v.w};
            *(bf16x4*)(xb + i) = o;
        }
    }
}

// 128x128x64 bf16 MFMA GEMM (R9-verified: counted-vmcnt double buffer).
__global__ __launch_bounds__(256, 2) void gemm_bf16_k(const bf16* __restrict__ A,
                                                   const bf16* __restrict__ Bw,
                                                   const float* __restrict__ bias,
                                                   const float* __restrict__ bias2,
                                                   float* __restrict__ C0,
                                                   bf16* __restrict__ CK,
                                                   bf16* __restrict__ CV,
                                                   int M, int N, int K, int mode, int Ns)
{
    __shared__ __align__(16) bf16 As[2][128 * 64];
    __shared__ __align__(16) bf16 Bs[2][128 * 64];
    const int tid = threadIdx.x;
    const int w = tid >> 6, l = tid & 63;
    const int wr = w >> 1, wc = w & 1;
    const int lc = l & 15, lg = l >> 4;
    const int row0 = blockIdx.y * 128, col0 = blockIdx.x * 128;

    f32x4 acc[4][4] = {};

    const int nk = K >> 6;
    auto issue = [&](int buf, int k0) {
        #pragma unroll
        for (int i = 0; i < 4; ++i) {
            const int br = (w * 4 + i) * 8;
            const int r = br + (l >> 3);
            const int gs = (l & 7) ^ (r & 7);
            gld16(&As[buf][br * 64], A  + (size_t)(row0 + r) * K + k0 + gs * 8);
            gld16(&Bs[buf][br * 64], Bw + (size_t)(col0 + r) * K + k0 + gs * 8);
        }
    };

    issue(0, 0);
    int cur = 0;
    for (int kt = 0; kt < nk; ++kt) {
        if (kt + 1 < nk) {
            issue(cur ^ 1, (kt + 1) << 6);
            asm volatile("s_waitcnt vmcnt(8)" ::: "memory");
        } else {
            asm volatile("s_waitcnt vmcnt(0)" ::: "memory");
        }
        __builtin_amdgcn_s_barrier();
        #pragma unroll
        for (int ks = 0; ks < 2; ++ks) {
            bf16x8 af[4], bfv[4];
            #pragma unroll
            for (int i = 0; i < 4; ++i) {
                af[i]  = *(const bf16x8*)&As[cur][swz(wr * 64 + i * 16 + lc, ks * 4 + lg)];
                bfv[i] = *(const bf16x8*)&Bs[cur][swz(wc * 64 + i * 16 + lc, ks * 4 + lg)];
            }
            #pragma unroll
            for (int mi = 0; mi < 4; ++mi)
                #pragma unroll
                for (int ni = 0; ni < 4; ++ni)
                    acc[mi][ni] = __builtin_amdgcn_mfma_f32_16x16x32_bf16(af[mi], bfv[ni], acc[mi][ni], 0, 0, 0);
        }
        asm volatile("s_waitcnt lgkmcnt(0)" ::: "memory");
        __builtin_amdgcn_s_barrier();
        cur ^= 1;
    }

    #pragma unroll
    for (int ni = 0; ni < 4; ++ni) {
        const int col = col0 + wc * 64 + ni * 16 + lc;
        #pragma unroll
        for (int mi = 0; mi < 4; ++mi) {
            const int rowb = row0 + wr * 64 + mi * 16 + lg * 4;
            f32x4 v = acc[mi][ni];
            if (mode == 0) {
                const float bv = bias[col];
                #pragma unroll
                for (int r = 0; r < 4; ++r)
                    C0[(size_t)(rowb + r) * N + col] = v[r] + bv;
            } else if (col < Ns) {
                const float bv = bias[col];
                #pragma unroll
                for (int r = 0; r < 4; ++r)
                    CK[(size_t)(rowb + r) * Ns + col] = (bf16)fmaxf(v[r] + bv, 0.f);
            } else {
                const float bv = bias2[col - Ns];
                const int b = rowb >> 11, tt = rowb & 2047;   // T = 2048
                bf16x4 o = {(bf16)(v[0] + bv), (bf16)(v[1] + bv),
                            (bf16)(v[2] + bv), (bf16)(v[3] + bv)};
                *(bf16x4*)(CV + ((size_t)b * Ns + (col - Ns)) * 2048 + tt) = o;
            }
        }
    }
}

// one SWAPPED QK -> softmax -> PV step on the staged 64x64 W/V tile.
// S^T = mfma(A=W^T s-rows, B=K q-cols): sv[st][r] = S[s=st*16+lg*4+r][q=wq*16+lc]
// P stored [q=16][s=64] stride 64 (R13-verified layout: pure-XOR swizzle is
// bank-balanced; stride-72 experiment (R14) PROVED additive+XOR mixing makes
// 4-way conflicts - do not reintroduce).
// T5: setprio(1) around the MFMA clusters (m191: attn-positive regime here).
__device__ __forceinline__ void tile_step(bf16x8 kf0, bf16x8 kf1,
                                          const bf16* Wb, const bf16* Vb,
                                          bf16* Pw, const float* b2l, int s0,
                                          f32x4 (&acc)[4], float& lsum,
                                          bool diag, int lc, int lg, int wq)
{
    // S^T = W . K + b2 (bias varies along s = MFMA rows = f32x4 elements)
    f32x4 sv[4];
    #pragma unroll
    for (int st = 0; st < 4; ++st) {
        const float4 b4 = *(const float4*)&b2l[s0 + st * 16 + lg * 4];
        sv[st] = {b4.x, b4.y, b4.z, b4.w};
    }
    __builtin_amdgcn_s_setprio(1);
    #pragma unroll
    for (int st = 0; st < 4; ++st) {
        bf16x8 wb0 = *(const bf16x8*)&Wb[swz(st * 16 + lc, lg)];
        bf16x8 wb1 = *(const bf16x8*)&Wb[swz(st * 16 + lc, 4 + lg)];
        sv[st] = __builtin_amdgcn_mfma_f32_16x16x32_bf16(wb0, kf0, sv[st], 0, 0, 0);
        sv[st] = __builtin_amdgcn_mfma_f32_16x16x32_bf16(wb1, kf1, sv[st], 0, 0, 0);
    }
    __builtin_amdgcn_s_setprio(0);
    // exp (exact, no max: |S| bounded small), causal mask, packed P write
    const int qv = wq * 16 + lc;
    #pragma unroll
    for (int st = 0; st < 4; ++st) {
        float e[4];
        #pragma unroll
        for (int r = 0; r < 4; ++r) {
            const int sidx = st * 16 + lg * 4 + r;
            float ev = __expf(sv[st][r]);
            if (diag && sidx > qv) ev = 0.f;
            e[r] = ev;
            lsum += ev;
        }
        bf16x4 pw = {(bf16)e[0], (bf16)e[1], (bf16)e[2], (bf16)e[3]};
        const int chunk = st * 2 + (lg >> 1);
        *(bf16x4*)&Pw[lc * 64 + ((chunk ^ (lc & 7)) << 3) + ((lg & 1) << 2)] = pw;
    }
    // O += P . V
    __builtin_amdgcn_s_setprio(1);
    #pragma unroll
    for (int ks = 0; ks < 2; ++ks) {
        bf16x8 pf = *(const bf16x8*)&Pw[swz(lc, ks * 4 + lg)];
        #pragma unroll
        for (int dt = 0; dt < 4; ++dt) {
            bf16x8 vv = *(const bf16x8*)&Vb[swz(dt * 16 + lc, ks * 4 + lg)];
            acc[dt] = __builtin_amdgcn_mfma_f32_16x16x32_bf16(pf, vv, acc[dt], 0, 0, 0);
        }
    }
    __builtin_amdgcn_s_setprio(0);
}

// v9 structure (R9/R13-verified, best measured): 512 threads; waves 0-3 ->
// q-tile 31-j, waves 4-7 -> q-tile j, shared 3-buffer W/V ring, counted vmcnt,
// b2 in LDS, swapped-QK packed-P tile_step (+setprio only this round).
__global__ __launch_bounds__(512, 4) void synth_attn_v9(const bf16* __restrict__ Kb,
                                                        const bf16* __restrict__ VT,
                                                        const bf16* __restrict__ w2t,
                                                        const float* __restrict__ b2,
                                                        bf16* __restrict__ Ob)
{
    constexpr int T = 2048, C = 1024, M = 2048;
    __shared__ __align__(16) bf16 Wl[3][64 * 64];
    __shared__ __align__(16) bf16 Vl[3][64 * 64];
    __shared__ __align__(16) bf16 Pl[8][16 * 64];
    __shared__ float b2l[M];
    const int tid = threadIdx.x;
    const int w = tid >> 6, l = tid & 63;
    const int lc = l & 15, lg = l >> 4;
    const int wq = w & 3, wt = w >> 2;

    const int bx = blockIdx.x;
    const int j = bx & 15;
    const int bh = bx >> 4;
    const int h = bh & 15, b = bh >> 4;
    const int tA = j, tB = 31 - j;
    const int myT = wt ? tA : tB;
    const int t0 = myT * 64;

    // b2 -> LDS (512 threads x 4 floats = 2048)
    *(float4*)&b2l[tid * 4] = *(const float4*)(b2 + tid * 4);
    __syncthreads();

    const bf16* Wgt = w2t + (size_t)h * M * 64;            // [s][64] rows
    const bf16* Vgt = VT + ((size_t)b * C + h * 64) * T;   // [d][T] rows
    bf16* Pw = &Pl[w][0];

    // K fragments for this wave's 16 q-rows (B-operand of swapped QK)
    const bf16* Kg = Kb + (size_t)(b * T + t0 + wq * 16 + lc) * C + h * 64;
    const bf16x8 kf0 = *(const bf16x8*)(Kg + lg * 8);
    const bf16x8 kf1 = *(const bf16x8*)(Kg + 32 + lg * 8);

    // prologue: stage tiles 0 and 1 (tB >= 16, both exist)
    stage8(&Wl[0][0], Wgt, 64, w, l);
    stage8(&Vl[0][0], Vgt, T, w, l);
    stage8(&Wl[1][0], Wgt + (size_t)64 * 64, 64, w, l);
    stage8(&Vl[1][0], Vgt + 64, T, w, l);

    f32x4 acc[4] = {};
    float lsum = 0.f;

    int cur = 0;
    for (int sb = 0; sb <= tB; ++sb) {
        const int s0 = sb * 64;
        // my 2 loads for tile sb done; tile sb+1's 2 may stay in flight
        if (sb < tB) asm volatile("s_waitcnt vmcnt(2)" ::: "memory");
        else         asm volatile("s_waitcnt vmcnt(0)" ::: "memory");
        __builtin_amdgcn_s_barrier();

        if (sb <= myT)
            tile_step(kf0, kf1, &Wl[cur][0], &Vl[cur][0], Pw, b2l, s0,
                      acc, lsum, sb == myT, lc, lg, wq);

        // stage tile sb+2 into buf (sb+2)%3: its readers crossed this barrier
        if (sb + 2 <= tB) {
            int nx = cur + 2; if (nx >= 3) nx -= 3;
            stage8(&Wl[nx][0], Wgt + (size_t)(s0 + 128) * 64, 64, w, l);
            stage8(&Vl[nx][0], Vgt + (s0 + 128), T, w, l);
        }
        if (++cur == 3) cur = 0;
    }

    // epilogue: lane's lsum is the partial row-sum for q=wq*16+lc; reduce over
    // the 4 lanes sharing lc (xor 16/32), then redistribute to the acc layout
    // (q = lg*4+r) via shfl from lane q.
    float ls = lsum;
    ls += __shfl_xor(ls, 16);
    ls += __shfl_xor(ls, 32);
    #pragma unroll
    for (int r = 0; r < 4; ++r) {
        const float inv = 1.f / __shfl(ls, lg * 4 + r);
        bf16* dst = Ob + (size_t)(b * T + t0 + wq * 16 + lg * 4 + r) * C + h * 64;
        #pragma unroll
        for (int dt = 0; dt < 4; ++dt)
            dst[dt * 16 + lc] = (bf16)(acc[dt][r] * inv);
    }
}

extern "C" void kernel_launch(void* const* d_in, const int* in_sizes, int n_in,
                              void* d_out, int out_size, void* d_ws, size_t ws_size,
                              hipStream_t stream) {
    const float* x       = (const float*)d_in[0];
    const float* w1_w    = (const float*)d_in[1];
    const float* w1_b    = (const float*)d_in[2];
    const float* w2      = (const float*)d_in[3];
    const float* b2      = (const float*)d_in[4];
    const float* value_w = (const float*)d_in[5];
    const float* value_b = (const float*)d_in[6];
    const float* proj_w  = (const float*)d_in[7];
    const float* proj_b  = (const float*)d_in[8];

    const int B = 2, T = 2048, C = 1024, H = 16, M = 2048;
    const int R = B * T;   // 4096

    bf16* xb  = (bf16*)d_ws;                  // [R][C]
    bf16* w1b = xb  + (size_t)R * C;          // [C][C]   } contiguous ->
    bf16* vwb = w1b + (size_t)C * C;          // [C][C]   } fused B [2C][C]
    bf16* w2t = vwb + (size_t)C * C;          // [H][M][64]
    bf16* pwb = w2t + (size_t)H * M * 64;     // [C][C]
    bf16* Kb  = pwb + (size_t)C * C;          // [R][C]
    bf16* VTb = Kb  + (size_t)R * C;          // [B][C][T]
    bf16* Ob  = VTb + (size_t)R * C;          // [R][C]    total 42 MB

    // one prep launch: w2 transpose + 3 weight casts + x cast
    prep_all_k<<<2048, 256, 0, stream>>>(x, xb, w1_w, w1b, value_w, vwb,
                                         proj_w, pwb, w2, w2t, R * C, C * C);

    // fused K/V GEMM: N = 2C, B-operand = [w1b ; vwb]
    gemm_bf16_k<<<dim3(2 * C / 128, R / 128), 256, 0, stream>>>(
        xb, w1b, w1_b, value_b, nullptr, Kb, VTb, R, 2 * C, C, 1, C);

    synth_attn_v9<<<dim3(512), 512, 0, stream>>>(Kb, VTb, w2t, b2, Ob);

    gemm_bf16_k<<<dim3(C / 128, R / 128), 256, 0, stream>>>(
        Ob, pwb, proj_b, nullptr, (float*)d_out, nullptr, nullptr, R, C, C, 0, C);
}